// Round 17
// baseline (84.798 us; speedup 1.0000x reference)
//
#include <hip/hip_runtime.h>
#include <hip/hip_bf16.h>

#define NSEQ 4096
#define FT 256
#define BKB 128

typedef __attribute__((ext_vector_type(8))) short bf16x8;
typedef __attribute__((ext_vector_type(4))) float f32x4;

__device__ __forceinline__ ushort f2bf(float f) {
  __hip_bfloat16 h = __float2bfloat16(f);
  return *reinterpret_cast<const ushort*>(&h);
}

// XOR swizzle of 16B granules within a 128B row.
__device__ __forceinline__ int swz(int row, int byteInRow) {
  return row * 128 + (byteInRow ^ ((row & 7) << 4));
}

// ---------------- Kernel A: seqT[b][f][n] = bf16(seq[b][n][f]) ----------------
__global__ __launch_bounds__(512) void transpose_cast_kernel(
    const float* __restrict__ seq, ushort* __restrict__ seqT) {
  __shared__ __align__(16) ushort lT[256 * 72];  // 36 KB

  const int tid = threadIdx.x;
  const int batch = blockIdx.x >> 6;
  const int n0 = (blockIdx.x & 63) * 64;
  const float* src = seq + ((size_t)batch * NSEQ + n0) * FT;

  const int ar = tid >> 3, ac = tid & 7;  // row 0..63, chunk 0..7
#pragma unroll
  for (int p = 0; p < 8; ++p) {
    const int fb = (ac + p * 8) * 4;
    f32x4 v = *reinterpret_cast<const f32x4*>(src + (size_t)ar * FT + fb);
#pragma unroll
    for (int e = 0; e < 4; ++e) lT[(fb + e) * 72 + ar] = f2bf(v[e]);
  }
  __syncthreads();
  const int f = tid >> 1, hf = tid & 1;
  ushort* dst = seqT + ((size_t)(batch * FT + f)) * NSEQ + n0 + hf * 32;
#pragma unroll
  for (int k = 0; k < 4; ++k) {
    uint4 v = *reinterpret_cast<const uint4*>(&lT[f * 72 + hf * 32 + k * 8]);
    *reinterpret_cast<uint4*>(dst + k * 8) = v;
  }
}

// ---------------- Kernel B: out = PReLU((adj @ seq) @ W^T + b*rowsum(adj)) --------------
// R16 structure with 2-deep A reg prefetch + fully counted waits (never 0
// until tail): body = issueB(t+1); issueA(t+2); mma; vmcnt(12) [retires
// A(t+1)]; writeA; vmcnt(4) [retires B(t+1), A(t+2) stays in flight across
// the barrier]; barrier.
__global__ __launch_bounds__(512) void bmm_prelu_kernel(
    const float* __restrict__ adj, const ushort* __restrict__ seqT,
    const float* __restrict__ W, const float* __restrict__ bias,
    const float* __restrict__ alphaP, float* __restrict__ out) {
  __shared__ __align__(16) char smem[2 * 65536 + 2 * 16384];  // lB[2] | lA[2]

  const int tid = threadIdx.x;
  const int lane = tid & 63;
  const int wid = tid >> 6;
  const int wm = wid >> 2, wn = wid & 3;

  const int bid = blockIdx.x;
  const int sbid = (bid & 7) * 32 + (bid >> 3);
  const int batch = sbid >> 6;
  const int m0 = (sbid & 63) * 64;

  const float* adjB = adj + (size_t)batch * NSEQ * NSEQ + (size_t)m0 * NSEQ;
  const ushort* hTB = seqT + (size_t)batch * FT * NSEQ;

  auto lB = [&](int i) -> char* { return smem + i * 65536; };
  auto lA = [&](int i) -> char* { return smem + 131072 + i * 16384; };

  const int arow = tid >> 3, ac = tid & 7;
  const int bro = (lane >> 4);
  const int bhalf = (lane >> 3) & 1;
  f32x4 rS0[4], rS1[4];
  float rsum = 0.f;  // per-thread partial rowsum of adj row `arow`

  f32x4 acc[2][4];
  const f32x4 zero = {0.f, 0.f, 0.f, 0.f};
#pragma unroll
  for (int mi = 0; mi < 2; ++mi)
#pragma unroll
    for (int ni = 0; ni < 4; ++ni) acc[mi][ni] = zero;

  auto issueA = [&](int t, f32x4* r) {
    const int k0 = t * BKB;
#pragma unroll
    for (int q = 0; q < 4; ++q)
      r[q] = *reinterpret_cast<const f32x4*>(
          adjB + (size_t)arow * NSEQ + k0 + ac * 16 + q * 4);
  };
  auto issueB = [&](int t, int ib) {
    const int k0 = t * BKB;
#pragma unroll
    for (int p = 0; p < 8; ++p) {
      const int grow = wid * 32 + p * 4 + bro;
      const int gsrc = (lane & 7) ^ (((p & 1) * 4 + bro) & 7);
      const ushort* gp = hTB + (size_t)grow * NSEQ + k0 + bhalf * 64 + gsrc * 8;
      char* lp = lB(ib) + wid * 8192 + p * 1024;
      __builtin_amdgcn_global_load_lds(
          (const __attribute__((address_space(1))) void*)gp,
          (__attribute__((address_space(3))) void*)lp, 16, 0, 0);
    }
  };
  auto writeA = [&](const f32x4* r, int ia) {
    char* lAp = lA(ia);
    const int half = ac >> 2;
#pragma unroll
    for (int q = 0; q < 4; ++q) {
      rsum += r[q][0] + r[q][1] + r[q][2] + r[q][3];
      ushort4 u = make_ushort4(f2bf(r[q][0]), f2bf(r[q][1]),
                               f2bf(r[q][2]), f2bf(r[q][3]));
      const int gih = (((ac & 3) * 2 + (q >> 1)) ^ (arow & 7));
      *reinterpret_cast<ushort4*>(lAp + arow * 256 + half * 128 + gih * 16 +
                                  (q & 1) * 8) = u;
    }
  };
  auto mma32 = [&](const char* lAp, const char* lBp) {
    const int r16 = lane & 15;
    const int sub = lane >> 4;
#pragma unroll
    for (int kk = 0; kk < 4; ++kk) {
      const int half = kk >> 1;
      const int gih = (((kk & 1) * 4 + sub) ^ (r16 & 7));
      const int bofs = half * 128 + gih * 16;
      bf16x8 a[2], b[4];
#pragma unroll
      for (int mi = 0; mi < 2; ++mi) {
        const int row = wm * 32 + mi * 16 + r16;
        a[mi] = *reinterpret_cast<const bf16x8*>(lAp + row * 256 + bofs);
      }
#pragma unroll
      for (int ni = 0; ni < 4; ++ni) {
        const int row = wn * 64 + ni * 16 + r16;
        b[ni] = *reinterpret_cast<const bf16x8*>(lBp + row * 256 + bofs);
      }
#pragma unroll
      for (int mi = 0; mi < 2; ++mi)
#pragma unroll
        for (int ni = 0; ni < 4; ++ni)
          acc[mi][ni] = __builtin_amdgcn_mfma_f32_16x16x32_bf16(
              a[mi], b[ni], acc[mi][ni], 0, 0, 0);
    }
  };

  // Prologue: B0(8), A0(4), A1(4) = 16 outstanding.
  issueB(0, 0);
  __builtin_amdgcn_sched_barrier(0);
  issueA(0, rS0);
  __builtin_amdgcn_sched_barrier(0);
  issueA(1, rS1);
  __builtin_amdgcn_sched_barrier(0);
  asm volatile("s_waitcnt vmcnt(4)" ::: "memory");  // retires B0 + A0; A1 in flight
  __builtin_amdgcn_sched_barrier(0);
  writeA(rS0, 0);
  asm volatile("s_waitcnt lgkmcnt(0)" ::: "memory");
  __builtin_amdgcn_s_barrier();
  __builtin_amdgcn_sched_barrier(0);

  // body(t): entering outstanding = [A(t+1):4].
  //   issueB(t+1)->lB(cur^1): [A(t+1):4][B(t+1):8]
  //   issueA(t+2)->rIss:      +4 = 16
  //   mma tile t;  vmcnt(12) retires A(t+1);  writeA->lA(cur^1);
  //   vmcnt(4) retires B(t+1) fully, leaves A(t+2) across the barrier.
  auto body = [&](int t, int cur, f32x4* rIss, const f32x4* rWr) {
    issueB(t + 1, cur ^ 1);
    __builtin_amdgcn_sched_barrier(0);
    issueA(t + 2, rIss);
    __builtin_amdgcn_sched_barrier(0);
    __builtin_amdgcn_s_setprio(1);
    mma32(lA(cur), lB(cur));
    __builtin_amdgcn_s_setprio(0);
    asm volatile("s_waitcnt vmcnt(12)" ::: "memory");
    __builtin_amdgcn_sched_barrier(0);
    writeA(rWr, cur ^ 1);
    asm volatile("s_waitcnt vmcnt(4)" ::: "memory");
    asm volatile("s_waitcnt lgkmcnt(0)" ::: "memory");
    __builtin_amdgcn_s_barrier();
    __builtin_amdgcn_sched_barrier(0);
  };

  // t = 0..29 (30 bodies; issue into rS[t&1], write from rS[(t+1)&1]).
  for (int j = 0; j < 15; ++j) {
    body(2 * j, 0, rS0, rS1);
    body(2 * j + 1, 1, rS1, rS0);
  }
  {  // t = 30 (cur = 0): no A issue. Entering [A31:4].
    issueB(31, 1);  // [A31:4][B31:8] = 12
    __builtin_amdgcn_sched_barrier(0);
    __builtin_amdgcn_s_setprio(1);
    mma32(lA(0), lB(0));
    __builtin_amdgcn_s_setprio(0);
    asm volatile("s_waitcnt vmcnt(8)" ::: "memory");  // retires A31
    __builtin_amdgcn_sched_barrier(0);
    writeA(rS1, 1);
    asm volatile("s_waitcnt vmcnt(0) lgkmcnt(0)" ::: "memory");  // tail drain
    __builtin_amdgcn_s_barrier();
    __builtin_amdgcn_sched_barrier(0);
  }
  // t = 31
  __builtin_amdgcn_s_setprio(1);
  mma32(lA(1), lB(1));
  __builtin_amdgcn_s_setprio(0);

  // ---------------- Epilogue: out = PReLU(tmp @ W^T + bias*rowsum) ----------------
  const float alpha = *alphaP;
  __syncthreads();

  // Phase 1: tmp (fp32 acc) -> bf16 LDS [64][264]; rowsum partials.
  ushort* lT64 = (ushort*)smem;           // 33792 B at [0, 33792)
  float* rsP = (float*)(smem + 98304);    // [64][8] partials (2 KB)
  float* rsW = (float*)(smem + 100352);   // [64] reduced
  const int TP2 = 264;
#pragma unroll
  for (int mi = 0; mi < 2; ++mi) {
    const int rbase = wm * 32 + mi * 16 + ((lane >> 4) << 2);
#pragma unroll
    for (int ni = 0; ni < 4; ++ni) {
      const int f = wn * 64 + ni * 16 + (lane & 15);
#pragma unroll
      for (int j = 0; j < 4; ++j) lT64[(rbase + j) * TP2 + f] = f2bf(acc[mi][ni][j]);
    }
  }
  rsP[arow * 8 + ac] = rsum;
  __syncthreads();
  if (tid < 64) {
    float s = 0.f;
#pragma unroll
    for (int i = 0; i < 8; ++i) s += rsP[tid * 8 + i];
    rsW[tid] = s;
  }

  // Phase 2: 4 chunks of W (64 f each): stage + GEMM.
  ushort* lW = (ushort*)(smem + 49152);   // [256][64] bf16 swz, 32 KB
  f32x4 accO[2][4];
#pragma unroll
  for (int mi = 0; mi < 2; ++mi)
#pragma unroll
    for (int ni = 0; ni < 4; ++ni) accO[mi][ni] = zero;
  const int war = tid >> 4, wac = tid & 15;
  for (int c = 0; c < 4; ++c) {
    __syncthreads();  // prior chunk's reads done before overwrite
    f32x4 rW[8];
#pragma unroll
    for (int p = 0; p < 8; ++p)
      rW[p] = *reinterpret_cast<const f32x4*>(
          W + (size_t)(war + p * 32) * FT + c * 64 + wac * 4);
#pragma unroll
    for (int p = 0; p < 8; ++p) {
      ushort4 u = make_ushort4(f2bf(rW[p][0]), f2bf(rW[p][1]),
                               f2bf(rW[p][2]), f2bf(rW[p][3]));
      *reinterpret_cast<ushort4*>((char*)lW + swz(war + p * 32, wac * 8)) = u;
    }
    __syncthreads();
    const int r16 = lane & 15;
    const int g16 = (lane >> 4) * 16;
#pragma unroll
    for (int kk = 0; kk < 2; ++kk) {
      const int kb = kk * 64 + g16;                        // byte off (B side)
      const int fo = c * 64 + kk * 32 + (lane >> 4) * 8;   // elem off (A side)
      bf16x8 a[2], b[4];
#pragma unroll
      for (int mi = 0; mi < 2; ++mi) {
        const int row = wm * 32 + mi * 16 + r16;
        a[mi] = *reinterpret_cast<const bf16x8*>(&lT64[row * TP2 + fo]);
      }
#pragma unroll
      for (int ni = 0; ni < 4; ++ni) {
        const int row = wn * 64 + ni * 16 + r16;
        b[ni] = *reinterpret_cast<const bf16x8*>((char*)lW + swz(row, kb));
      }
#pragma unroll
      for (int mi = 0; mi < 2; ++mi)
#pragma unroll
        for (int ni = 0; ni < 4; ++ni)
          accO[mi][ni] = __builtin_amdgcn_mfma_f32_16x16x32_bf16(
              a[mi], b[ni], accO[mi][ni], 0, 0, 0);
    }
  }

  // Phase 3: bias*rowsum + PReLU -> LDS overlay -> coalesced rows.
  __syncthreads();
  float* lo = (float*)smem;
  const int PITCH = 264;
#pragma unroll
  for (int mi = 0; mi < 2; ++mi) {
    const int rbase = wm * 32 + mi * 16 + ((lane >> 4) << 2);
#pragma unroll
    for (int ni = 0; ni < 4; ++ni) {
      const int o = wn * 64 + ni * 16 + (lane & 15);
      const float bo = bias[o];
#pragma unroll
      for (int j = 0; j < 4; ++j) {
        float v = accO[mi][ni][j] + bo * rsW[rbase + j];
        v = v > 0.f ? v : alpha * v;
        lo[(rbase + j) * PITCH + o] = v;
      }
    }
  }
  __syncthreads();
  float* outB = out + ((size_t)batch * NSEQ + m0) * FT;
  const int r = tid >> 3, c8 = tid & 7;
#pragma unroll
  for (int k = 0; k < 8; ++k) {
    const int g = c8 + k * 8;
    f32x4 v = *reinterpret_cast<const f32x4*>(lo + r * PITCH + g * 4);
    __builtin_nontemporal_store(v, reinterpret_cast<f32x4*>(outB + (size_t)r * FT + g * 4));
  }
}

extern "C" void kernel_launch(void* const* d_in, const int* in_sizes, int n_in,
                              void* d_out, int out_size, void* d_ws, size_t ws_size,
                              hipStream_t stream) {
  const float* seq = (const float*)d_in[0];
  const float* adj = (const float*)d_in[1];
  const float* W = (const float*)d_in[2];
  const float* bias = (const float*)d_in[3];
  const float* alpha = (const float*)d_in[4];
  float* out = (float*)d_out;
  ushort* seqT = (ushort*)d_ws;  // [4][256][4096] bf16 = 8 MB

  transpose_cast_kernel<<<256, 512, 0, stream>>>(seq, seqT);
  bmm_prelu_kernel<<<256, 512, 0, stream>>>(adj, seqT, W, bias, alpha, out);
}